// Round 1
// baseline (935.577 us; speedup 1.0000x reference)
//
#include <hip/hip_runtime.h>
#include <hip/hip_bf16.h>

// MPNN layer, fp32, restructured:
//   P[n] = [ h2[n]@W1a + b1 | h2[n]@W1c ]          (node_pre)
//   hidden_e = ReLU(P_A[src] + e@W1b + P_C[dst])    (edge kernel, scatter-add to Hsum[dst], deg[dst]+=1)
//   h_new = ReLU(Hsum@(W2@U1a) + deg*(b2@U1a) + h@U1b + c1)@U2 + c2   (update kernel)
// Identity used: segment_sum(ReLU(pre)@W2 + b2) = segment_sum(ReLU(pre))@W2 + deg*b2
// and m_sum@U1a = Hsum@(W2@U1a) + deg*(b2@U1a).

#define NPAD 65   // 64 + 1 pad -> LDS bank-conflict-free column access

__device__ __forceinline__ void lds_fence() {
    // per-wave LDS phase boundary: drain ds ops, stop compiler reordering
    asm volatile("s_waitcnt lgkmcnt(0)" ::: "memory");
}

// ---------------------------------------------------------------------------
// K0: Wp = W2 @ U1a  (64x64),  bvec = b2 @ U1a (64)
// ---------------------------------------------------------------------------
__global__ void combine_kernel(const float* __restrict__ W2, const float* __restrict__ b2,
                               const float* __restrict__ U1, float* __restrict__ Wp,
                               float* __restrict__ bvec) {
    int k = blockIdx.x;        // 0..63
    int cc = threadIdx.x;      // 0..63
    float a = 0.f;
    for (int c = 0; c < 64; ++c) a = fmaf(W2[k * 64 + c], U1[c * 64 + cc], a);
    Wp[k * 64 + cc] = a;
    if (k == 0) {
        float bv = 0.f;
        for (int c = 0; c < 64; ++c) bv = fmaf(b2[c], U1[c * 64 + cc], bv);
        bvec[cc] = bv;
    }
}

// ---------------------------------------------------------------------------
// K1: node precompute.  P[n][0:64] = h2[n]@W1a + b1 ; P[n][64:128] = h2[n]@W1c
// h2[n] = [h[n](64) | rnf[n](64)].  W1a = W1 rows 0..127, W1c = rows 192..319.
// Scheme: wave = 64 rows, lane = row. Activations staged transposed in LDS,
// weights are wave-uniform (scalar loads). Two K-chunks (h then rnf) share LDS.
// ---------------------------------------------------------------------------
__global__ __launch_bounds__(256) void node_pre_kernel(
    const float* __restrict__ h, const float* __restrict__ rnf,
    const float* __restrict__ W1, const float* __restrict__ b1,
    float* __restrict__ P, int N) {
    __shared__ float lds[4][64 * NPAD];
    const int wid = threadIdx.x >> 6, lane = threadIdx.x & 63;
    const int tile = blockIdx.x * 4 + wid;
    const int R0 = tile * 64;
    if (R0 >= N) return;
    const int nvalid = min(64, N - R0);
    float* L = lds[wid];

    float accA[64], accC[64];
#pragma unroll
    for (int c = 0; c < 64; ++c) { accA[c] = 0.f; accC[c] = 0.f; }

    for (int half = 0; half < 2; ++half) {
        const float* X = half ? rnf : h;
        // stage rows transposed: L[ch*NPAD + r] = X[R0+r][ch]
        if (nvalid == 64) {
            for (int r4 = 0; r4 < 16; ++r4) {
                const float4 v = ((const float4*)(X + ((size_t)R0 + 4 * r4) * 64))[lane];
                int rr = 4 * r4 + (lane >> 4);
                int ch = (lane & 15) * 4;
                L[(ch + 0) * NPAD + rr] = v.x;
                L[(ch + 1) * NPAD + rr] = v.y;
                L[(ch + 2) * NPAD + rr] = v.z;
                L[(ch + 3) * NPAD + rr] = v.w;
            }
        } else {
            for (int r = 0; r < nvalid; ++r)
                L[lane * NPAD + r] = X[((size_t)R0 + r) * 64 + lane];
        }
        lds_fence();
        const float* Wa = W1 + (size_t)(half * 64) * 64;         // rows half*64..+63
        const float* Wc = W1 + (size_t)(192 + half * 64) * 64;   // rows 192+half*64..
        for (int k = 0; k < 64; ++k) {
            float x = L[k * NPAD + lane];
#pragma unroll
            for (int c = 0; c < 64; ++c) accA[c] = fmaf(x, Wa[k * 64 + c], accA[c]);
#pragma unroll
            for (int c = 0; c < 64; ++c) accC[c] = fmaf(x, Wc[k * 64 + c], accC[c]);
        }
        lds_fence();
    }
#pragma unroll
    for (int c = 0; c < 64; ++c) accA[c] += b1[c];

    // transpose-store A half
#pragma unroll
    for (int c = 0; c < 64; ++c) L[c * NPAD + lane] = accA[c];
    lds_fence();
    for (int r = 0; r < nvalid; ++r)
        P[((size_t)R0 + r) * 128 + lane] = L[lane * NPAD + r];
    lds_fence();
    // transpose-store C half
#pragma unroll
    for (int c = 0; c < 64; ++c) L[c * NPAD + lane] = accC[c];
    lds_fence();
    for (int r = 0; r < nvalid; ++r)
        P[((size_t)R0 + r) * 128 + 64 + lane] = L[lane * NPAD + r];
}

// ---------------------------------------------------------------------------
// K2: edge kernel. Per 64-edge tile (1 wave):
//   stage e tile transposed (+ copy e to out), Eb = e@W1b (lane=edge),
//   transpose Eb, then per edge-row (coalesced, lane=channel):
//   hidden = ReLU(Eb + P_A[src] + P_C[dst]); atomicAdd into Hsum[dst]; deg[dst]+=1.
// ---------------------------------------------------------------------------
__global__ __launch_bounds__(256) void edge_kernel(
    const float* __restrict__ e, const int* __restrict__ src, const int* __restrict__ dst,
    const float* __restrict__ W1, const float* __restrict__ P,
    float* __restrict__ Hsum, float* __restrict__ deg,
    float* __restrict__ e_out, int E) {
    __shared__ float lds[4][64 * NPAD];
    const int wid = threadIdx.x >> 6, lane = threadIdx.x & 63;
    const int tile = blockIdx.x * 4 + wid;
    const int E0 = tile * 64;
    if (E0 >= E) return;
    const int evalid = min(64, E - E0);
    float* L = lds[wid];

    // stage e transposed + copy out
    if (evalid == 64) {
        for (int r4 = 0; r4 < 16; ++r4) {
            const float4 v = ((const float4*)(e + ((size_t)E0 + 4 * r4) * 64))[lane];
            ((float4*)(e_out + ((size_t)E0 + 4 * r4) * 64))[lane] = v;
            int rr = 4 * r4 + (lane >> 4);
            int ch = (lane & 15) * 4;
            L[(ch + 0) * NPAD + rr] = v.x;
            L[(ch + 1) * NPAD + rr] = v.y;
            L[(ch + 2) * NPAD + rr] = v.z;
            L[(ch + 3) * NPAD + rr] = v.w;
        }
    } else {
        for (int r = 0; r < evalid; ++r) {
            float v = e[((size_t)E0 + r) * 64 + lane];
            e_out[((size_t)E0 + r) * 64 + lane] = v;
            L[lane * NPAD + r] = v;
        }
    }
    lds_fence();

    // Eb[lane(edge)][c] = sum_k e[edge][k] * W1b[k][c]
    float acc[64];
#pragma unroll
    for (int c = 0; c < 64; ++c) acc[c] = 0.f;
    const float* Wb = W1 + (size_t)128 * 64;   // rows 128..191
    for (int k = 0; k < 64; ++k) {
        float x = L[k * NPAD + lane];
#pragma unroll
        for (int c = 0; c < 64; ++c) acc[c] = fmaf(x, Wb[k * 64 + c], acc[c]);
    }
    lds_fence();

    // transpose Eb into LDS (e tile is dead)
#pragma unroll
    for (int c = 0; c < 64; ++c) L[c * NPAD + lane] = acc[c];
    lds_fence();

    int vsrc = (lane < evalid) ? src[E0 + lane] : 0;
    int vdst = (lane < evalid) ? dst[E0 + lane] : 0;
    for (int r = 0; r < evalid; ++r) {
        int sr = __builtin_amdgcn_readlane(vsrc, r);
        int dr = __builtin_amdgcn_readlane(vdst, r);
        float hv = L[lane * NPAD + r]                 // Eb[r][lane]
                 + P[(size_t)sr * 128 + lane]         // A' (incl b1)
                 + P[(size_t)dr * 128 + 64 + lane];   // C
        hv = fmaxf(hv, 0.f);
        unsafeAtomicAdd(&Hsum[(size_t)dr * 64 + lane], hv);
        if (lane == 0) unsafeAtomicAdd(&deg[dr], 1.0f);
    }
}

// ---------------------------------------------------------------------------
// K3: update kernel.  h1 = ReLU(Hsum@Wp + deg*bvec + h@U1b + c1); out = h1@U2 + c2
// lane = row; second matvec keeps h1 per-lane via LDS transpose round-trip.
// ---------------------------------------------------------------------------
__global__ __launch_bounds__(256) void update_kernel(
    const float* __restrict__ Hsum, const float* __restrict__ deg, const float* __restrict__ h,
    const float* __restrict__ Wp, const float* __restrict__ bvec,
    const float* __restrict__ U1, const float* __restrict__ c1,
    const float* __restrict__ U2, const float* __restrict__ c2,
    float* __restrict__ out, int N) {
    __shared__ float lds[4][64 * NPAD];
    const int wid = threadIdx.x >> 6, lane = threadIdx.x & 63;
    const int tile = blockIdx.x * 4 + wid;
    const int R0 = tile * 64;
    if (R0 >= N) return;
    const int nvalid = min(64, N - R0);
    float* L = lds[wid];

    float acc[64];
#pragma unroll
    for (int c = 0; c < 64; ++c) acc[c] = 0.f;

    for (int half = 0; half < 2; ++half) {
        const float* X = half ? h : Hsum;
        const float* W = half ? (U1 + (size_t)64 * 64) : Wp;   // U1b = U1 rows 64..127
        if (nvalid == 64) {
            for (int r4 = 0; r4 < 16; ++r4) {
                const float4 v = ((const float4*)(X + ((size_t)R0 + 4 * r4) * 64))[lane];
                int rr = 4 * r4 + (lane >> 4);
                int ch = (lane & 15) * 4;
                L[(ch + 0) * NPAD + rr] = v.x;
                L[(ch + 1) * NPAD + rr] = v.y;
                L[(ch + 2) * NPAD + rr] = v.z;
                L[(ch + 3) * NPAD + rr] = v.w;
            }
        } else {
            for (int r = 0; r < nvalid; ++r)
                L[lane * NPAD + r] = X[((size_t)R0 + r) * 64 + lane];
        }
        lds_fence();
        for (int k = 0; k < 64; ++k) {
            float x = L[k * NPAD + lane];
#pragma unroll
            for (int c = 0; c < 64; ++c) acc[c] = fmaf(x, W[k * 64 + c], acc[c]);
        }
        lds_fence();
    }

    float dg = (lane < nvalid) ? deg[R0 + lane] : 0.f;   // lane = row
    // h1 = ReLU(acc + dg*bvec + c1), store transposed
#pragma unroll
    for (int c = 0; c < 64; ++c) {
        float h1 = fmaxf(fmaf(dg, bvec[c], acc[c] + c1[c]), 0.f);
        L[c * NPAD + lane] = h1;
    }
    lds_fence();

    // second matvec: acc2[cc] = c2[cc] + sum_k h1[row=lane][k] * U2[k][cc]
    float acc2[64];
#pragma unroll
    for (int cc = 0; cc < 64; ++cc) acc2[cc] = c2[cc];
    for (int k = 0; k < 64; ++k) {
        float x = L[k * NPAD + lane];
#pragma unroll
        for (int cc = 0; cc < 64; ++cc) acc2[cc] = fmaf(x, U2[k * 64 + cc], acc2[cc]);
    }
    lds_fence();

    // transpose-store h_new
#pragma unroll
    for (int c = 0; c < 64; ++c) L[c * NPAD + lane] = acc2[c];
    lds_fence();
    for (int r = 0; r < nvalid; ++r)
        out[((size_t)R0 + r) * 64 + lane] = L[lane * NPAD + r];
}

// ---------------------------------------------------------------------------
extern "C" void kernel_launch(void* const* d_in, const int* in_sizes, int n_in,
                              void* d_out, int out_size, void* d_ws, size_t ws_size,
                              hipStream_t stream) {
    const float* h   = (const float*)d_in[0];
    const float* e   = (const float*)d_in[1];
    const float* rnf = (const float*)d_in[2];
    const int*   src = (const int*)d_in[3];
    const int*   dst = (const int*)d_in[4];
    const float* W1  = (const float*)d_in[5];
    const float* b1  = (const float*)d_in[6];
    const float* W2  = (const float*)d_in[7];
    const float* b2  = (const float*)d_in[8];
    const float* U1  = (const float*)d_in[9];
    const float* c1  = (const float*)d_in[10];
    const float* U2  = (const float*)d_in[11];
    const float* c2  = (const float*)d_in[12];

    const int N = in_sizes[0] / 64;
    const int E = in_sizes[1] / 64;

    float* out_h = (float*)d_out;
    float* out_e = out_h + (size_t)N * 64;

    float* P    = (float*)d_ws;              // N*128
    float* Hsum = P + (size_t)N * 128;       // N*64
    float* degp = Hsum + (size_t)N * 64;     // N
    float* Wp   = degp + N;                  // 64*64
    float* bvec = Wp + 64 * 64;              // 64

    hipMemsetAsync(Hsum, 0, (size_t)N * 64 * sizeof(float), stream);
    hipMemsetAsync(degp, 0, (size_t)N * sizeof(float), stream);

    combine_kernel<<<64, 64, 0, stream>>>(W2, b2, U1, Wp, bvec);

    const int ntiles = (N + 63) / 64;
    node_pre_kernel<<<(ntiles + 3) / 4, 256, 0, stream>>>(h, rnf, W1, b1, P, N);

    const int etiles = (E + 63) / 64;
    edge_kernel<<<(etiles + 3) / 4, 256, 0, stream>>>(e, src, dst, W1, P, Hsum, degp, out_e, E);

    update_kernel<<<(ntiles + 3) / 4, 256, 0, stream>>>(Hsum, degp, h, Wp, bvec, U1, c1, U2, c2, out_h, N);
}